// Round 1
// baseline (9636.062 us; speedup 1.0000x reference)
//
#include <hip/hip_runtime.h>

__device__ __forceinline__ float sigf(float x) { return 1.0f / (1.0f + __expf(-x)); }

// ---------------- transpose: out[(off + c)*out_ld + r] = in[r*C + c] ----------------
__global__ void transpose_kernel(const float* __restrict__ in, float* __restrict__ out,
                                 int R, int C, int out_ld, int out_row_off)
{
    __shared__ float tl[32][33];
    int tx = threadIdx.x, ty = threadIdx.y;             // block (32,8)
    int c0 = blockIdx.x * 32, r0 = blockIdx.y * 32;
#pragma unroll
    for (int i = 0; i < 4; i++) {
        int r = r0 + ty + i * 8, c = c0 + tx;
        if (r < R && c < C) tl[ty + i * 8][tx] = in[(size_t)r * C + c];
    }
    __syncthreads();
#pragma unroll
    for (int i = 0; i < 4; i++) {
        int c = c0 + ty + i * 8, r = r0 + tx;           // out row = c, out col = r
        if (r < R && c < C)
            out[(size_t)(out_row_off + c) * out_ld + r] = tl[tx][ty + i * 8];
    }
}

// ---------------- bcomb = b_ih + b_hh ; zero h0/c0 accumulators ----------------
__global__ void prep_kernel(const float* __restrict__ b_ih, const float* __restrict__ b_hh,
                            float* __restrict__ bcomb, float* __restrict__ xh,
                            float* __restrict__ cbuf)
{
    int idx = blockIdx.x * 256 + threadIdx.x;
    if (idx < 2048) bcomb[idx] = b_ih[idx] + b_hh[idx];
    int e = idx - 2048;
    if (e >= 0 && e < 65536) {
        int n = e >> 10, r = e & 1023;                  // 64 n x (512 h + 512 c)
        if (r < 512) xh[(size_t)n * 2560 + 2048 + r] = 0.0f;
        else         cbuf[(size_t)n * 512 + (r - 512)] = 0.0f;
    }
}

// ---------------- generic GEMM: C[m][j] = sum_k A[m][k] * BT[k][j] ----------------
// block: 256 threads; j-tile 64 (tid&63), 4 m-groups (tid>>6) of MPT rows each.
// MODE: 0 = store + bias, 1 = atomicAdd (K-split), 2 = fc store with (t,n)->(n,t) remap + bias
template <int MPT, int MODE>
__global__ void gemm_kernel(const float* __restrict__ A, int lda,
                            const float* __restrict__ BT, int ldb,
                            float* __restrict__ C, int ldc,
                            const float* __restrict__ bias,
                            int M, int J, int K, int kchunk)
{
    constexpr int MT = MPT * 4;
    __shared__ float lds_a[MT * 32];
    const int tid = threadIdx.x;
    const int j   = blockIdx.x * 64 + (tid & 63);
    const int mg  = tid >> 6;
    const int m0  = blockIdx.y * MT;
    const int k0  = blockIdx.z * kchunk;
    const int k1  = min(k0 + kchunk, K);
    const bool jin = (j < J);

    float acc[MPT];
#pragma unroll
    for (int r = 0; r < MPT; r++) acc[r] = 0.0f;

    for (int kc = k0; kc < k1; kc += 32) {
        __syncthreads();
#pragma unroll
        for (int i = tid; i < MT * 32; i += 256) {
            int row = i >> 5, col = i & 31;
            lds_a[i] = A[(size_t)(m0 + row) * lda + kc + col];
        }
        __syncthreads();
#pragma unroll 8
        for (int kk = 0; kk < 32; kk++) {
            float w = jin ? BT[(size_t)(kc + kk) * ldb + j] : 0.0f;
#pragma unroll
            for (int r = 0; r < MPT; r++)
                acc[r] += lds_a[(mg * MPT + r) * 32 + kk] * w;
        }
    }
    if (jin) {
#pragma unroll
        for (int r = 0; r < MPT; r++) {
            int row = m0 + mg * MPT + r;
            if (MODE == 1) {
                atomicAdd(&C[(size_t)row * ldc + j], acc[r]);
            } else if (MODE == 2) {
                int n = row & 63, tt = row >> 6;        // row = t*64 + n
                C[(size_t)(n * 32 + tt) * ldc + j] = acc[r] + bias[j];
            } else {
                C[(size_t)row * ldc + j] = acc[r] + bias[j];
            }
        }
    }
}

// ---------------- fused per-step kernel: LSTM update (prev step) + attention + x_t ----------------
// grid = 64 blocks (one per batch row n), 256 threads
__global__ void attn_step_kernel(const float* __restrict__ features,
                                 const float* __restrict__ attn_img,
                                 const float* __restrict__ AtkWT,
                                 const float* __restrict__ atk_b,
                                 const float* __restrict__ full_W,
                                 const float* __restrict__ full_b,
                                 const float* __restrict__ embd_W,
                                 const int*   __restrict__ captions,
                                 const float* __restrict__ bcomb,
                                 float* __restrict__ xh,
                                 float* __restrict__ cbuf,
                                 float* __restrict__ gates,
                                 float* __restrict__ h_out,
                                 int t)
{
    __shared__ float lds_h[512];
    __shared__ float lds_ah[512];
    __shared__ float lds_fw[512];
    __shared__ float lds_red[256];
    __shared__ float lds_logit[64];

    const int n = blockIdx.x, tid = threadIdx.x;
    const int wid = tid >> 6, lane = tid & 63;

    // ---- Phase U: LSTM update using gates from step t-1 ----
    if (t > 0) {
        for (int hh = tid; hh < 512; hh += 256) {
            float gi = gates[(size_t)n * 2048 + hh];
            float gf = gates[(size_t)n * 2048 + 512 + hh];
            float gg = gates[(size_t)n * 2048 + 1024 + hh];
            float go = gates[(size_t)n * 2048 + 1536 + hh];
            float cold = cbuf[(size_t)n * 512 + hh];
            float cn = sigf(gf) * cold + sigf(gi) * tanhf(gg);
            float hn = sigf(go) * tanhf(cn);
            cbuf[(size_t)n * 512 + hh] = cn;
            xh[(size_t)n * 2560 + 2048 + hh] = hn;
            h_out[(size_t)((t - 1) * 64 + n) * 512 + hh] = hn;
        }
    }
    __syncthreads();

    // ---- Phase 0: re-init gates row to combined bias for this step ----
    for (int jj = tid; jj < 2048; jj += 256) gates[(size_t)n * 2048 + jj] = bcomb[jj];

    // ---- Phase 1: stage h and attn_full_W in LDS ----
    for (int k = tid; k < 512; k += 256) {
        lds_h[k]  = xh[(size_t)n * 2560 + 2048 + k];
        lds_fw[k] = full_W[k];
    }
    __syncthreads();

    // ---- Phase 2: attn_h[a] = atk_b[a] + sum_k h[k] * attn_token_W[a][k] ----
    {
        float a0 = atk_b[tid], a1 = atk_b[tid + 256];
#pragma unroll 4
        for (int k = 0; k < 512; k++) {
            float hk = lds_h[k];
            a0 += hk * AtkWT[(size_t)k * 512 + tid];
            a1 += hk * AtkWT[(size_t)k * 512 + tid + 256];
        }
        lds_ah[tid] = a0;
        lds_ah[tid + 256] = a1;
    }
    __syncthreads();

    // ---- Phase 3: scores[p] = sum_a relu(attn_h[a] + attn_img[n,p,a]) * full_W[a] ----
    for (int p = 0; p < 64; p++) {
        const float* img = attn_img + (size_t)(n * 64 + p) * 512;
        float e0 = fmaxf(lds_ah[tid] + img[tid], 0.0f);
        float e1 = fmaxf(lds_ah[tid + 256] + img[tid + 256], 0.0f);
        float part = e0 * lds_fw[tid] + e1 * lds_fw[tid + 256];
#pragma unroll
        for (int off = 32; off > 0; off >>= 1) part += __shfl_down(part, off, 64);
        if (lane == 0) lds_red[p * 4 + wid] = part;
    }
    __syncthreads();

    // ---- Phase 3b: softmax over p (first wave) ----
    if (tid < 64) {
        float s = lds_red[tid * 4] + lds_red[tid * 4 + 1] + lds_red[tid * 4 + 2] +
                  lds_red[tid * 4 + 3] + full_b[0];
        float m = s;
#pragma unroll
        for (int off = 32; off > 0; off >>= 1) m = fmaxf(m, __shfl_xor(m, off, 64));
        float e = __expf(s - m);
        float sum = e;
#pragma unroll
        for (int off = 32; off > 0; off >>= 1) sum += __shfl_xor(sum, off, 64);
        lds_logit[tid] = e / sum;
    }
    __syncthreads();

    // ---- Phase 4: ctx[c] = sum_p logit[p] * features[n,p,c] -> xh[n][0:1536] ----
    for (int cc = tid; cc < 1536; cc += 256) {
        const float* f = features + (size_t)(n * 64) * 1536 + cc;
        float acc = 0.0f;
#pragma unroll 8
        for (int p = 0; p < 64; p++) acc += lds_logit[p] * f[(size_t)p * 1536];
        xh[(size_t)n * 2560 + cc] = acc;
    }

    // ---- Phase 5: embedding -> xh[n][1536:2048] ----
    int cap = captions[n * 32 + t];
    for (int e = tid; e < 512; e += 256)
        xh[(size_t)n * 2560 + 1536 + e] = embd_W[(size_t)cap * 512 + e];
}

// ---------------- final LSTM update producing h_out[31] ----------------
__global__ void final_update_kernel(const float* __restrict__ gates,
                                    const float* __restrict__ cbuf,
                                    float* __restrict__ h_out)
{
    int idx = blockIdx.x * 256 + threadIdx.x;       // 32768 total
    int n = idx >> 9, hh = idx & 511;
    float gi = gates[(size_t)n * 2048 + hh];
    float gf = gates[(size_t)n * 2048 + 512 + hh];
    float gg = gates[(size_t)n * 2048 + 1024 + hh];
    float go = gates[(size_t)n * 2048 + 1536 + hh];
    float cold = cbuf[(size_t)n * 512 + hh];
    float cn = sigf(gf) * cold + sigf(gi) * tanhf(gg);
    float hn = sigf(go) * tanhf(cn);
    h_out[(size_t)(31 * 64 + n) * 512 + hh] = hn;
}

extern "C" void kernel_launch(void* const* d_in, const int* in_sizes, int n_in,
                              void* d_out, int out_size, void* d_ws, size_t ws_size,
                              hipStream_t stream)
{
    const float* features = (const float*)d_in[0];
    const int*   captions = (const int*)d_in[1];
    const float* embd_W   = (const float*)d_in[2];
    const float* atk_W    = (const float*)d_in[3];
    const float* atk_b    = (const float*)d_in[4];
    const float* af_W     = (const float*)d_in[5];
    const float* af_b     = (const float*)d_in[6];
    const float* full_W   = (const float*)d_in[7];
    const float* full_b   = (const float*)d_in[8];
    const float* W_ih     = (const float*)d_in[9];
    const float* b_ih     = (const float*)d_in[10];
    const float* W_hh     = (const float*)d_in[11];
    const float* b_hh     = (const float*)d_in[12];
    const float* fc_W     = (const float*)d_in[13];
    const float* fc_b     = (const float*)d_in[14];
    const float* init_Wh  = (const float*)d_in[15];
    const float* init_Wc  = (const float*)d_in[16];
    float* out = (float*)d_out;

    float* ws = (float*)d_ws;
    float* WcombT   = ws; ws += 2560 * 2048;   // [k 0..2559][j 0..2047]: W_ih^T then W_hh^T
    float* AtkWT    = ws; ws += 512 * 512;     // [k][a]
    float* AfWT     = ws; ws += 1536 * 512;    // [c][a]
    float* fcWT     = ws; ws += 512 * 10000;   // [k][v]
    float* bcomb    = ws; ws += 2048;
    float* attn_img = ws; ws += 4096 * 512;    // [(n*64+p)][a]
    float* xh       = ws; ws += 64 * 2560;     // [n][ctx 1536 | emb 512 | h 512]
    float* cbuf     = ws; ws += 64 * 512;
    float* gates    = ws; ws += 64 * 2048;
    float* h_out    = ws; ws += 32 * 64 * 512; // [(t*64+n)][h]

    dim3 tb(32, 8);
    transpose_kernel<<<dim3(64, 64),  tb, 0, stream>>>(W_ih,  WcombT, 2048, 2048, 2048, 0);
    transpose_kernel<<<dim3(16, 64),  tb, 0, stream>>>(W_hh,  WcombT, 2048, 512,  2048, 2048);
    transpose_kernel<<<dim3(16, 16),  tb, 0, stream>>>(atk_W, AtkWT,  512,  512,  512,  0);
    transpose_kernel<<<dim3(48, 16),  tb, 0, stream>>>(af_W,  AfWT,   512,  1536, 512,  0);
    transpose_kernel<<<dim3(16, 313), tb, 0, stream>>>(fc_W,  fcWT,   10000, 512, 10000, 0);
    prep_kernel<<<264, 256, 0, stream>>>(b_ih, b_hh, bcomb, xh, cbuf);

    // attn_img = features @ attn_feat_W^T + attn_feat_b   (4096 x 512, K=1536)
    gemm_kernel<4, 0><<<dim3(8, 256, 1), 256, 0, stream>>>(
        features, 1536, AfWT, 512, attn_img, 512, af_b, 4096, 512, 1536, 1536);
    // h0 / c0: K=98304 split 192 ways, atomic accumulate (init_W already k-major)
    gemm_kernel<16, 1><<<dim3(8, 1, 192), 256, 0, stream>>>(
        features, 98304, init_Wh, 512, xh + 2048, 2560, nullptr, 64, 512, 98304, 512);
    gemm_kernel<16, 1><<<dim3(8, 1, 192), 256, 0, stream>>>(
        features, 98304, init_Wc, 512, cbuf, 512, nullptr, 64, 512, 98304, 512);

    for (int t = 0; t < 32; t++) {
        attn_step_kernel<<<64, 256, 0, stream>>>(features, attn_img, AtkWT, atk_b,
                                                 full_W, full_b, embd_W, captions,
                                                 bcomb, xh, cbuf, gates, h_out, t);
        // gates += [ctx|emb|h] @ WcombT  (64 x 2048, K=2560, 5-way K-split, atomic)
        gemm_kernel<4, 1><<<dim3(32, 4, 5), 256, 0, stream>>>(
            xh, 2560, WcombT, 2048, gates, 2048, nullptr, 64, 2048, 2560, 512);
    }
    final_update_kernel<<<128, 256, 0, stream>>>(gates, cbuf, h_out);

    // preds[n][t][v] = h_out[t*64+n][:] . fc_W[v][:] + fc_b[v]
    gemm_kernel<16, 2><<<dim3(157, 32, 1), 256, 0, stream>>>(
        h_out, 512, fcWT, 10000, out, 10000, fc_b, 2048, 10000, 512, 512);
}

// Round 2
// 4363.829 us; speedup vs baseline: 2.2082x; 2.2082x over previous
//
#include <hip/hip_runtime.h>

__device__ __forceinline__ float sigf(float x) { return 1.0f / (1.0f + __expf(-x)); }

// ---------------- transpose: out[c*out_ld + r] = in[r*C + c] (used for atk_W only) ----
__global__ void __launch_bounds__(256) transpose_kernel(
    const float* __restrict__ in, float* __restrict__ out, int R, int C, int out_ld)
{
    __shared__ float tl[32][33];
    int tx = threadIdx.x, ty = threadIdx.y;             // block (32,8)
    int c0 = blockIdx.x * 32, r0 = blockIdx.y * 32;
#pragma unroll
    for (int i = 0; i < 4; i++) {
        int r = r0 + ty + i * 8, c = c0 + tx;
        if (r < R && c < C) tl[ty + i * 8][tx] = in[(size_t)r * C + c];
    }
    __syncthreads();
#pragma unroll
    for (int i = 0; i < 4; i++) {
        int c = c0 + ty + i * 8, r = r0 + tx;
        if (r < R && c < C) out[(size_t)c * out_ld + r] = tl[tx][ty + i * 8];
    }
}

__global__ void __launch_bounds__(256) prep_bcomb(const float* __restrict__ b_ih,
                                                  const float* __restrict__ b_hh,
                                                  float* __restrict__ bcomb)
{
    int i = blockIdx.x * 256 + threadIdx.x;
    if (i < 2048) bcomb[i] = b_ih[i] + b_hh[i];
}

// ---------------- generic NT GEMM: C[m][j] = sum_k A[m][k]*B[j][k] + bias[j] ----------
// tile 128m x 64j, 256 threads, 8x4 micro-tile. A row-major lda, B j-major ldb.
// GATHER: A row m -> embd_W[caps[(m&63)*32 + (m>>6)]]. REMAP: out row = (m&63)*32+(m>>6).
template <int GATHER, int REMAP>
__global__ void __launch_bounds__(256) gemm_nt(
    const float* __restrict__ A, int lda, const float* __restrict__ B, int ldb,
    const int* __restrict__ caps, const float* __restrict__ bias,
    float* __restrict__ C, int ldc, int J, int K)
{
    __shared__ float la[32 * 132];      // [kk][m], pad 128->132
    __shared__ float lb[32 * 68];       // [kk][j], pad 64->68
    const int tid = threadIdx.x;
    const int m0 = blockIdx.x * 128, j0 = blockIdx.y * 64;
    const int tx = tid & 15, ty = tid >> 4;
    float acc[8][4] = {};

    for (int k0 = 0; k0 < K; k0 += 32) {
        __syncthreads();
        {   // stage A: 128 rows x 32 k, transposed into la
            int r0 = tid >> 3, c4 = (tid & 7) * 4;
#pragma unroll
            for (int p = 0; p < 4; p++) {
                int m = m0 + r0 + p * 32;
                int arow = GATHER ? caps[(m & 63) * 32 + (m >> 6)] : m;
                const float4 v = *(const float4*)&A[(size_t)arow * lda + k0 + c4];
#pragma unroll
                for (int q = 0; q < 4; q++) la[(c4 + q) * 132 + r0 + p * 32] = ((const float*)&v)[q];
            }
        }
        {   // stage B: 64 j-rows x 32 k, transposed into lb
            int r0 = tid >> 3, c4 = (tid & 7) * 4;
#pragma unroll
            for (int p = 0; p < 2; p++) {
                int j = j0 + r0 + p * 32;
                if (j >= J) j = J - 1;
                const float4 v = *(const float4*)&B[(size_t)j * ldb + k0 + c4];
#pragma unroll
                for (int q = 0; q < 4; q++) lb[(c4 + q) * 68 + r0 + p * 32] = ((const float*)&v)[q];
            }
        }
        __syncthreads();
#pragma unroll
        for (int kk = 0; kk < 32; kk++) {
            float bv[4];
            *(float4*)bv = *(const float4*)&lb[kk * 68 + tx * 4];
#pragma unroll
            for (int pi = 0; pi < 2; pi++) {
                float av[4];
                *(float4*)av = *(const float4*)&la[kk * 132 + ty * 8 + pi * 4];
#pragma unroll
                for (int i = 0; i < 4; i++)
#pragma unroll
                    for (int jj = 0; jj < 4; jj++)
                        acc[pi * 4 + i][jj] += av[i] * bv[jj];
            }
        }
    }
    const int j = j0 + tx * 4;
#pragma unroll
    for (int pi = 0; pi < 2; pi++)
#pragma unroll
        for (int i = 0; i < 4; i++) {
            int m = m0 + ty * 8 + pi * 4 + i;
            int orow = REMAP ? ((m & 63) * 32 + (m >> 6)) : m;
#pragma unroll
            for (int jj = 0; jj < 4; jj++)
                if (j + jj < J)
                    C[(size_t)orow * ldc + j + jj] = acc[pi * 4 + i][jj] + bias[j + jj];
        }
}

// ---------------- init GEMM: [h0|c0] partials.  grid (16 j-tiles, 48 k-chunks) --------
// C_part[kc][64][1024] = features[64 x 2048-chunk] @ (init_Wh|init_Wc)[chunk][64 j]
__global__ void __launch_bounds__(256) init_gemm(
    const float* __restrict__ features, const float* __restrict__ Wh,
    const float* __restrict__ Wc, float* __restrict__ ipart)
{
    __shared__ float la[32 * 68];
    __shared__ float lb[32 * 68];
    const int tid = threadIdx.x;
    const int jg0 = blockIdx.x * 64, kc = blockIdx.y;
    const float* Bsrc = (jg0 < 512) ? Wh : Wc;
    const int j0 = (jg0 < 512) ? jg0 : jg0 - 512;
    const int tx = tid & 15, ty = tid >> 4;
    float acc[4][4] = {};

    for (int kt = 0; kt < 64; kt++) {
        const int k0 = kc * 2048 + kt * 32;
        __syncthreads();
        {   // A: features, 64 rows, lda 98304 (transposed store)
            int r0 = tid >> 3, c4 = (tid & 7) * 4;
#pragma unroll
            for (int p = 0; p < 2; p++) {
                const float4 v = *(const float4*)&features[(size_t)(r0 + p * 32) * 98304 + k0 + c4];
#pragma unroll
                for (int q = 0; q < 4; q++) la[(c4 + q) * 68 + r0 + p * 32] = ((const float*)&v)[q];
            }
        }
        {   // B: k-major [98304][512]; direct b128 store
            int kr = tid >> 4, j4 = (tid & 15) * 4;
#pragma unroll
            for (int p = 0; p < 2; p++) {
                const float4 v = *(const float4*)&Bsrc[(size_t)(k0 + kr + p * 16) * 512 + j0 + j4];
                *(float4*)&lb[(kr + p * 16) * 68 + j4] = v;
            }
        }
        __syncthreads();
#pragma unroll
        for (int kk = 0; kk < 32; kk++) {
            float av[4], bv[4];
            *(float4*)av = *(const float4*)&la[kk * 68 + ty * 4];
            *(float4*)bv = *(const float4*)&lb[kk * 68 + tx * 4];
#pragma unroll
            for (int i = 0; i < 4; i++)
#pragma unroll
                for (int jj = 0; jj < 4; jj++) acc[i][jj] += av[i] * bv[jj];
        }
    }
#pragma unroll
    for (int i = 0; i < 4; i++) {
        int m = ty * 4 + i;
#pragma unroll
        for (int jj = 0; jj < 4; jj++)
            ipart[(size_t)(kc * 64 + m) * 1024 + jg0 + tx * 4 + jj] = acc[i][jj];
    }
}

// ---------------- reduce init partials -> h0 (into xh[., 1536:2048]) and c0 -----------
__global__ void __launch_bounds__(256) init_reduce(const float* __restrict__ ipart,
                                                   float* __restrict__ xh,
                                                   float* __restrict__ cbuf)
{
    int idx = blockIdx.x * 256 + threadIdx.x;   // 65536
    int n = idx >> 10, jg = idx & 1023;
    float s = 0.0f;
#pragma unroll 8
    for (int kc = 0; kc < 48; kc++) s += ipart[(size_t)(kc * 64 + n) * 1024 + jg];
    if (jg < 512) xh[(size_t)n * 2048 + 1536 + jg] = s;
    else          cbuf[(size_t)n * 512 + (jg - 512)] = s;
}

// ---------------- per-step gates GEMM: gpart[kc] = xh @ [W_ih_ctx | W_hh]^T -----------
// grid (32 j-tiles, 8 k-chunks of 256). xh = [ctx 1536 | h 512], lda 2048.
__global__ void __launch_bounds__(256) gates_gemm(
    const float* __restrict__ xh, const float* __restrict__ W_ih,
    const float* __restrict__ W_hh, float* __restrict__ gpart)
{
    __shared__ float la[32 * 68];
    __shared__ float lb[32 * 68];
    const int tid = threadIdx.x;
    const int j0 = blockIdx.x * 64, kc = blockIdx.y;
    const int tx = tid & 15, ty = tid >> 4;
    float acc[4][4] = {};

    for (int kt = 0; kt < 8; kt++) {
        const int k0 = kc * 256 + kt * 32;
        __syncthreads();
        {   // A: xh 64 rows
            int r0 = tid >> 3, c4 = (tid & 7) * 4;
#pragma unroll
            for (int p = 0; p < 2; p++) {
                const float4 v = *(const float4*)&xh[(size_t)(r0 + p * 32) * 2048 + k0 + c4];
#pragma unroll
                for (int q = 0; q < 4; q++) la[(c4 + q) * 68 + r0 + p * 32] = ((const float*)&v)[q];
            }
        }
        {   // B: j-major dual-source (W_ih cols 0..1535 | W_hh cols 0..511)
            int r0 = tid >> 3, c4 = (tid & 7) * 4;
#pragma unroll
            for (int p = 0; p < 2; p++) {
                int j = j0 + r0 + p * 32;
                const float* src = (k0 < 1536) ? &W_ih[(size_t)j * 2048 + k0 + c4]
                                               : &W_hh[(size_t)j * 512 + (k0 - 1536) + c4];
                const float4 v = *(const float4*)src;
#pragma unroll
                for (int q = 0; q < 4; q++) lb[(c4 + q) * 68 + r0 + p * 32] = ((const float*)&v)[q];
            }
        }
        __syncthreads();
#pragma unroll
        for (int kk = 0; kk < 32; kk++) {
            float av[4], bv[4];
            *(float4*)av = *(const float4*)&la[kk * 68 + ty * 4];
            *(float4*)bv = *(const float4*)&lb[kk * 68 + tx * 4];
#pragma unroll
            for (int i = 0; i < 4; i++)
#pragma unroll
                for (int jj = 0; jj < 4; jj++) acc[i][jj] += av[i] * bv[jj];
        }
    }
#pragma unroll
    for (int i = 0; i < 4; i++) {
        int m = ty * 4 + i;
#pragma unroll
        for (int jj = 0; jj < 4; jj++)
            gpart[(size_t)(kc * 64 + m) * 2048 + j0 + tx * 4 + jj] = acc[i][jj];
    }
}

// ---------------- fused step: LSTM update (gates of t-1) + attention + ctx ------------
// grid = 64 blocks (one per n), 256 threads
__global__ void __launch_bounds__(256) attn_step_kernel(
    const float* __restrict__ features, const float* __restrict__ attn_img,
    const float* __restrict__ AtkWT, const float* __restrict__ atk_b,
    const float* __restrict__ full_W, const float* __restrict__ full_b,
    const float* __restrict__ emb_part, const float* __restrict__ gpart,
    float* __restrict__ xh, float* __restrict__ cbuf, float* __restrict__ h_out, int t)
{
    __shared__ float lds_h[512];
    __shared__ float lds_ah[512];
    __shared__ float lds_fw[512];
    __shared__ float lds_red[256];
    __shared__ float lds_logit[64];

    const int n = blockIdx.x, tid = threadIdx.x;
    const int wid = tid >> 6, lane = tid & 63;

    // ---- Phase U: reduce gate partials of step t-1, LSTM update ----
    if (t > 0) {
        for (int hh = tid; hh < 512; hh += 256) {
            float g[4];
#pragma unroll
            for (int q = 0; q < 4; q++) {
                float s = emb_part[(size_t)((t - 1) * 64 + n) * 2048 + q * 512 + hh];
#pragma unroll
                for (int kc = 0; kc < 8; kc++)
                    s += gpart[(size_t)(kc * 64 + n) * 2048 + q * 512 + hh];
                g[q] = s;
            }
            float cold = cbuf[(size_t)n * 512 + hh];
            float cn = sigf(g[1]) * cold + sigf(g[0]) * tanhf(g[2]);
            float hn = sigf(g[3]) * tanhf(cn);
            cbuf[(size_t)n * 512 + hh] = cn;
            xh[(size_t)n * 2048 + 1536 + hh] = hn;
            h_out[(size_t)((t - 1) * 64 + n) * 512 + hh] = hn;
            lds_h[hh] = hn;
        }
    } else {
        for (int hh = tid; hh < 512; hh += 256) lds_h[hh] = xh[(size_t)n * 2048 + 1536 + hh];
    }
    for (int k = tid; k < 512; k += 256) lds_fw[k] = full_W[k];
    __syncthreads();

    // ---- attn_h[a] = atk_b[a] + sum_k h[k] * atk_W[a][k]  (AtkWT is [k][a]) ----
    {
        float a0 = atk_b[tid], a1 = atk_b[tid + 256];
#pragma unroll 4
        for (int k = 0; k < 512; k++) {
            float hk = lds_h[k];
            a0 += hk * AtkWT[(size_t)k * 512 + tid];
            a1 += hk * AtkWT[(size_t)k * 512 + tid + 256];
        }
        lds_ah[tid] = a0;
        lds_ah[tid + 256] = a1;
    }
    __syncthreads();

    // ---- scores[p] = sum_a relu(attn_h[a] + attn_img[n,p,a]) * full_W[a] ----
    for (int p = 0; p < 64; p++) {
        const float* img = attn_img + (size_t)(n * 64 + p) * 512;
        float e0 = fmaxf(lds_ah[tid] + img[tid], 0.0f);
        float e1 = fmaxf(lds_ah[tid + 256] + img[tid + 256], 0.0f);
        float part = e0 * lds_fw[tid] + e1 * lds_fw[tid + 256];
#pragma unroll
        for (int off = 32; off > 0; off >>= 1) part += __shfl_down(part, off, 64);
        if (lane == 0) lds_red[p * 4 + wid] = part;
    }
    __syncthreads();

    // ---- softmax over p ----
    if (tid < 64) {
        float s = lds_red[tid * 4] + lds_red[tid * 4 + 1] + lds_red[tid * 4 + 2] +
                  lds_red[tid * 4 + 3] + full_b[0];
        float m = s;
#pragma unroll
        for (int off = 32; off > 0; off >>= 1) m = fmaxf(m, __shfl_xor(m, off, 64));
        float e = __expf(s - m);
        float sum = e;
#pragma unroll
        for (int off = 32; off > 0; off >>= 1) sum += __shfl_xor(sum, off, 64);
        lds_logit[tid] = e / sum;
    }
    __syncthreads();

    // ---- ctx[c] = sum_p logit[p] * features[n,p,c] -> xh[n][0:1536] ----
    for (int cc = tid; cc < 1536; cc += 256) {
        const float* f = features + (size_t)(n * 64) * 1536 + cc;
        float acc = 0.0f;
#pragma unroll 8
        for (int p = 0; p < 64; p++) acc += lds_logit[p] * f[(size_t)p * 1536];
        xh[(size_t)n * 2048 + cc] = acc;
    }
}

// ---------------- final LSTM update (gates of t=31) -> h_out row 31 -------------------
__global__ void __launch_bounds__(256) final_update_kernel(
    const float* __restrict__ gpart, const float* __restrict__ emb_part,
    const float* __restrict__ cbuf, float* __restrict__ h_out)
{
    int idx = blockIdx.x * 256 + threadIdx.x;   // 32768
    int n = idx >> 9, hh = idx & 511;
    float g[4];
#pragma unroll
    for (int q = 0; q < 4; q++) {
        float s = emb_part[(size_t)(31 * 64 + n) * 2048 + q * 512 + hh];
#pragma unroll
        for (int kc = 0; kc < 8; kc++)
            s += gpart[(size_t)(kc * 64 + n) * 2048 + q * 512 + hh];
        g[q] = s;
    }
    float cold = cbuf[(size_t)n * 512 + hh];
    float cn = sigf(g[1]) * cold + sigf(g[0]) * tanhf(g[2]);
    float hn = sigf(g[3]) * tanhf(cn);
    h_out[(size_t)(31 * 64 + n) * 512 + hh] = hn;
}

extern "C" void kernel_launch(void* const* d_in, const int* in_sizes, int n_in,
                              void* d_out, int out_size, void* d_ws, size_t ws_size,
                              hipStream_t stream)
{
    const float* features = (const float*)d_in[0];
    const int*   captions = (const int*)d_in[1];
    const float* embd_W   = (const float*)d_in[2];
    const float* atk_W    = (const float*)d_in[3];
    const float* atk_b    = (const float*)d_in[4];
    const float* af_W     = (const float*)d_in[5];
    const float* af_b     = (const float*)d_in[6];
    const float* full_W   = (const float*)d_in[7];
    const float* full_b   = (const float*)d_in[8];
    const float* W_ih     = (const float*)d_in[9];
    const float* b_ih     = (const float*)d_in[10];
    const float* W_hh     = (const float*)d_in[11];
    const float* b_hh     = (const float*)d_in[12];
    const float* fc_W     = (const float*)d_in[13];
    const float* fc_b     = (const float*)d_in[14];
    const float* init_Wh  = (const float*)d_in[15];
    const float* init_Wc  = (const float*)d_in[16];
    float* out = (float*)d_out;

    float* ws = (float*)d_ws;
    float* AtkWT    = ws; ws += 512 * 512;       // [k][a]
    float* bcomb    = ws; ws += 2048;
    float* attn_img = ws; ws += 4096 * 512;      // [(n*64+p)][a]
    float* emb_part = ws; ws += 2048 * 2048;     // [(t*64+n)][gate j] includes bcomb
    float* ipart    = ws; ws += 48 * 64 * 1024;  // init partials
    float* xh       = ws; ws += 64 * 2048;       // [n][ctx 1536 | h 512]
    float* cbuf     = ws; ws += 64 * 512;
    float* gpart    = ws; ws += 8 * 64 * 2048;   // per-step gate partials
    float* h_out    = ws; ws += 2048 * 512;      // [(t*64+n)][h]

    transpose_kernel<<<dim3(16, 16), dim3(32, 8), 0, stream>>>(atk_W, AtkWT, 512, 512, 512);
    prep_bcomb<<<8, 256, 0, stream>>>(b_ih, b_hh, bcomb);

    // attn_img = features @ af_W^T + af_b : M=4096, J=512, K=1536
    gemm_nt<0, 0><<<dim3(32, 8), 256, 0, stream>>>(
        features, 1536, af_W, 1536, nullptr, af_b, attn_img, 512, 512, 1536);
    // emb_part[t*64+n][j] = embd_W[cap[n][t]] @ W_ih[:,1536:]^T + bcomb : M=2048, J=2048, K=512
    gemm_nt<1, 0><<<dim3(16, 32), 256, 0, stream>>>(
        embd_W, 512, W_ih + 1536, 2048, captions, bcomb, emb_part, 2048, 2048, 512);
    // h0/c0 partials + reduce
    init_gemm<<<dim3(16, 48), 256, 0, stream>>>(features, init_Wh, init_Wc, ipart);
    init_reduce<<<256, 256, 0, stream>>>(ipart, xh, cbuf);

    for (int t = 0; t < 32; t++) {
        attn_step_kernel<<<64, 256, 0, stream>>>(features, attn_img, AtkWT, atk_b,
                                                 full_W, full_b, emb_part, gpart,
                                                 xh, cbuf, h_out, t);
        gates_gemm<<<dim3(32, 8), 256, 0, stream>>>(xh, W_ih, W_hh, gpart);
    }
    final_update_kernel<<<128, 256, 0, stream>>>(gpart, emb_part, cbuf, h_out);

    // preds: M=2048 (t*64+n), J=10000, K=512, remapped store to [n][t][v]
    gemm_nt<0, 1><<<dim3(16, 157), 256, 0, stream>>>(
        h_out, 512, fc_W, 512, nullptr, fc_b, out, 10000, 10000, 512);
}